// Round 5
// 238.386 us; speedup vs baseline: 1.0361x; 1.0361x over previous
//
#include <hip/hip_runtime.h>

// ConvTranspose2d, stride=2, pad=1, k=4, groups=24 (one channel each).
// x: [8,1,24,256,256] f32; w: [24,1,1,4,4] f32; b: [24] f32
// y: [8,1,24,512,512] f32
//
// Output row 2r   (ph=0): input rows {r-1, r}   weight rows {3, 1}
// Output row 2r+1 (ph=1): input rows {r,   r+1} weight rows {2, 0}
// Output col 2q   (pw=0): input cols {q-1, q}   weight cols {3, 1}
// Output col 2q+1 (pw=1): input cols {q,   q+1} weight cols {2, 0}
//
// v2b: fully-coalesced stores. Lane t computes output cols {4t..4t+3} and
// {256+4t..256+4t+3} of rows 2r/2r+1, so each of the 4 store instructions is
// 64 lanes x float4 = 1 KB CONTIGUOUS (full cache lines -> no partial-line
// RMW at L2/HBM, which the v1 32B-strided stores caused). Inputs: per row,
// two float2 loads (cols 2t..2t+1 and 128+2t..128+2t+1; 512 B contiguous per
// wave instruction), halo cols via __shfl incl. the 127/128 seam.
// Stores are nontemporal via __builtin_nontemporal_store on a NATIVE clang
// ext_vector float4 (HIP's float4 class type is rejected by the builtin).
// blockIdx.x is XCD-remapped (XCD = x%8 since gridDim.x=64) so the 3x row
// reuse hits one XCD's L2 instead of bouncing across chiplets.

#define NS 24
#define IH 256
#define IW 256
#define OHH 512
#define OWW 512

typedef float f32x4 __attribute__((ext_vector_type(4)));

__global__ __launch_bounds__(256) void convt2x_coal_kernel(
    const float* __restrict__ x, const float* __restrict__ w,
    const float* __restrict__ bias, float* __restrict__ out)
{
    const int b  = blockIdx.z;
    const int s  = blockIdx.y;
    // bijective XCD chunk remap: XCD = blockIdx.x % 8; give each XCD a
    // contiguous band of 8 blocks (32 row-pairs) per image.
    const int xr  = ((blockIdx.x & 7) << 3) | (blockIdx.x >> 3);
    const int lin = xr * 256 + threadIdx.x;          // 0 .. 16383
    const int t   = lin & 63;    // lane id
    const int r   = lin >> 6;    // input row-pair index, wave-uniform

    const float* ximg = x + (size_t)(b * NS + s) * IH * IW;

    // Weights + bias: block-uniform address -> scalar loads.
    const float* wv = w + s * 16;
    float W[16];
    #pragma unroll
    for (int k = 0; k < 16; ++k) W[k] = wv[k];
    const float bb = bias[s];

    // X[i][z][j]: input row r-1+i, col 128*z + 2t-1+j  (j=0..3)
    float X[3][2][4];
    #pragma unroll
    for (int i = 0; i < 3; ++i) {
        const int rr = r - 1 + i;                    // wave-uniform
        float2 mA = make_float2(0.f, 0.f);
        float2 mB = make_float2(0.f, 0.f);
        if (rr >= 0 && rr < IH) {                    // scalar branch (uniform)
            const float* row = ximg + (size_t)rr * IW;
            mA = *(const float2*)(row + 2 * t);          // cols 2t, 2t+1
            mB = *(const float2*)(row + 128 + 2 * t);    // cols 128+2t, 128+2t+1
        }
        const float sAy = __shfl(mA.y, (t - 1) & 63);    // col 2t-1
        const float sAx = __shfl(mA.x, (t + 1) & 63);    // col 2t+2
        const float sBy = __shfl(mB.y, (t - 1) & 63);    // col 128+2t-1
        const float sBx = __shfl(mB.x, (t + 1) & 63);    // col 128+2t+2
        const float c127 = __shfl(mA.y, 63);             // seam: col 127
        const float c128 = __shfl(mB.x, 0);              // seam: col 128

        X[i][0][0] = (t == 0)  ? 0.f  : sAy;
        X[i][0][1] = mA.x;
        X[i][0][2] = mA.y;
        X[i][0][3] = (t == 63) ? c128 : sAx;
        X[i][1][0] = (t == 0)  ? c127 : sBy;
        X[i][1][1] = mB.x;
        X[i][1][2] = mB.y;
        X[i][1][3] = (t == 63) ? 0.f  : sBx;
    }

    // ---- compute: 2 rows x (2 halves x 4 cols) ----
    float o0[2][4], o1[2][4];
    #pragma unroll
    for (int z = 0; z < 2; ++z) {
        o0[z][0] = X[0][z][0]*W[15] + X[0][z][1]*W[13]
                 + X[1][z][0]*W[7]  + X[1][z][1]*W[5]  + bb;
        o0[z][1] = X[0][z][1]*W[14] + X[0][z][2]*W[12]
                 + X[1][z][1]*W[6]  + X[1][z][2]*W[4]  + bb;
        o0[z][2] = X[0][z][1]*W[15] + X[0][z][2]*W[13]
                 + X[1][z][1]*W[7]  + X[1][z][2]*W[5]  + bb;
        o0[z][3] = X[0][z][2]*W[14] + X[0][z][3]*W[12]
                 + X[1][z][2]*W[6]  + X[1][z][3]*W[4]  + bb;
        o1[z][0] = X[1][z][0]*W[11] + X[1][z][1]*W[9]
                 + X[2][z][0]*W[3]  + X[2][z][1]*W[1]  + bb;
        o1[z][1] = X[1][z][1]*W[10] + X[1][z][2]*W[8]
                 + X[2][z][1]*W[2]  + X[2][z][2]*W[0]  + bb;
        o1[z][2] = X[1][z][1]*W[11] + X[1][z][2]*W[9]
                 + X[2][z][1]*W[3]  + X[2][z][2]*W[1]  + bb;
        o1[z][3] = X[1][z][2]*W[10] + X[1][z][3]*W[8]
                 + X[2][z][2]*W[2]  + X[2][z][3]*W[0]  + bb;
    }

    // ---- store: 4 x fully-contiguous 1KB wave stores, nontemporal ----
    float* obase = out + ((size_t)(b * NS + s) * OHH + 2 * r) * OWW;
    #pragma unroll
    for (int z = 0; z < 2; ++z) {
        f32x4 v0 = { o0[z][0], o0[z][1], o0[z][2], o0[z][3] };
        f32x4 v1 = { o1[z][0], o1[z][1], o1[z][2], o1[z][3] };
        __builtin_nontemporal_store(v0, (f32x4*)(obase + z * 256 + 4 * t));
        __builtin_nontemporal_store(v1, (f32x4*)(obase + OWW + z * 256 + 4 * t));
    }
}

extern "C" void kernel_launch(void* const* d_in, const int* in_sizes, int n_in,
                              void* d_out, int out_size, void* d_ws, size_t ws_size,
                              hipStream_t stream) {
    const float* x    = (const float*)d_in[0];
    const float* w    = (const float*)d_in[1];
    const float* bias = (const float*)d_in[2];
    float* out        = (float*)d_out;

    // per (b,s) image: 256 row-pairs x 64 lanes = 16384 threads -> 64 blocks of 256
    dim3 grid(64, NS, 8);
    convt2x_coal_kernel<<<grid, 256, 0, stream>>>(x, w, bias, out);
}

// Round 6
// 238.314 us; speedup vs baseline: 1.0365x; 1.0003x over previous
//
#include <hip/hip_runtime.h>

// ConvTranspose2d, stride=2, pad=1, k=4, groups=24 (one channel each).
// x: [8,1,24,256,256] f32; w: [24,1,1,4,4] f32; b: [24] f32
// y: [8,1,24,512,512] f32
//
// Output row 2r   (ph=0): input rows {r-1, r}   weight rows {3, 1}
// Output row 2r+1 (ph=1): input rows {r,   r+1} weight rows {2, 0}
// Output col 2q   (pw=0): input cols {q-1, q}   weight cols {3, 1}
// Output col 2q+1 (pw=1): input cols {q,   q+1} weight cols {2, 0}
//
// v3: register-rolling, RP=4 row-pairs per thread. v2b spent 6 loads +
// 18 ds_bpermute + addressing per 16 output floats, and re-loaded/re-shuffled
// every input row 3x (once per neighboring row-pair). Here each wave owns 4
// consecutive row-pairs and keeps a 3-row rolling window in registers:
//   - 6 row-loads per thread instead of 12 (read amp 3.0x -> 1.5x)
//   - halo shuffles computed ONCE per row (36 ds ops vs 72)
//   - per-output instruction overhead ~halved
// Stores: unchanged from v2b — lane t owns cols {4t..4t+3} per 256-col half,
// 4 x 1KB fully-contiguous nontemporal wave-stores per pair (16 KB contiguous
// per wave total). XCD-bijective block remap kept (grid.x=16, 16%8==0).

#define NS 24
#define IH 256
#define IW 256
#define OHH 512
#define OWW 512
#define RP 4

typedef float f32x4 __attribute__((ext_vector_type(4)));

// Load input row rr (zeros if OOB) into v[z][j] = col 128*z + 2t-1+j, j=0..3.
__device__ __forceinline__ void load_row(const float* __restrict__ ximg,
                                         int rr, int t, float v[2][4])
{
    float2 mA = make_float2(0.f, 0.f);
    float2 mB = make_float2(0.f, 0.f);
    if (rr >= 0 && rr < IH) {
        const float* row = ximg + (size_t)rr * IW;
        mA = *(const float2*)(row + 2 * t);          // cols 2t, 2t+1
        mB = *(const float2*)(row + 128 + 2 * t);    // cols 128+2t, 128+2t+1
    }
    const float sAy = __shfl(mA.y, (t - 1) & 63);    // col 2t-1
    const float sAx = __shfl(mA.x, (t + 1) & 63);    // col 2t+2
    const float sBy = __shfl(mB.y, (t - 1) & 63);    // col 128+2t-1
    const float sBx = __shfl(mB.x, (t + 1) & 63);    // col 128+2t+2
    const float c127 = __shfl(mA.y, 63);             // seam: col 127
    const float c128 = __shfl(mB.x, 0);              // seam: col 128

    v[0][0] = (t == 0)  ? 0.f  : sAy;
    v[0][1] = mA.x;
    v[0][2] = mA.y;
    v[0][3] = (t == 63) ? c128 : sAx;
    v[1][0] = (t == 0)  ? c127 : sBy;
    v[1][1] = mB.x;
    v[1][2] = mB.y;
    v[1][3] = (t == 63) ? 0.f  : sBx;
}

__global__ __launch_bounds__(256) void convt2x_roll_kernel(
    const float* __restrict__ x, const float* __restrict__ w,
    const float* __restrict__ bias, float* __restrict__ out)
{
    const int b   = blockIdx.z;
    const int s   = blockIdx.y;
    // bijective XCD chunk remap for gridDim.x=16: XCD = blockIdx.x % 8,
    // each XCD gets 2 consecutive chunks of 16 row-pairs.
    const int xr  = ((blockIdx.x & 7) << 1) | (blockIdx.x >> 3);
    const int t   = threadIdx.x & 63;    // lane id = column tile
    const int wid = threadIdx.x >> 6;    // wave in block, 0..3
    const int r0  = xr * 16 + wid * 4;   // first row-pair of this wave

    const float* ximg = x + (size_t)(b * NS + s) * IH * IW;

    // Weights + bias: block-uniform address -> scalar loads.
    const float* wv = w + s * 16;
    float W[16];
    #pragma unroll
    for (int k = 0; k < 16; ++k) W[k] = wv[k];
    const float bb = bias[s];

    // Rolling 3-row window. X[(p+0)%3]=row r-1, X[(p+1)%3]=row r, X[(p+2)%3]=row r+1.
    float X[3][2][4];
    load_row(ximg, r0 - 1, t, X[0]);
    load_row(ximg, r0,     t, X[1]);

    #pragma unroll
    for (int p = 0; p < RP; ++p) {
        const int r = r0 + p;
        load_row(ximg, r + 1, t, X[(p + 2) % 3]);   // static idx after unroll

        float (&T)[2][4] = X[(p + 0) % 3];   // row r-1
        float (&M)[2][4] = X[(p + 1) % 3];   // row r
        float (&B)[2][4] = X[(p + 2) % 3];   // row r+1

        float o0[2][4], o1[2][4];
        #pragma unroll
        for (int z = 0; z < 2; ++z) {
            o0[z][0] = T[z][0]*W[15] + T[z][1]*W[13]
                     + M[z][0]*W[7]  + M[z][1]*W[5]  + bb;
            o0[z][1] = T[z][1]*W[14] + T[z][2]*W[12]
                     + M[z][1]*W[6]  + M[z][2]*W[4]  + bb;
            o0[z][2] = T[z][1]*W[15] + T[z][2]*W[13]
                     + M[z][1]*W[7]  + M[z][2]*W[5]  + bb;
            o0[z][3] = T[z][2]*W[14] + T[z][3]*W[12]
                     + M[z][2]*W[6]  + M[z][3]*W[4]  + bb;
            o1[z][0] = M[z][0]*W[11] + M[z][1]*W[9]
                     + B[z][0]*W[3]  + B[z][1]*W[1]  + bb;
            o1[z][1] = M[z][1]*W[10] + M[z][2]*W[8]
                     + B[z][1]*W[2]  + B[z][2]*W[0]  + bb;
            o1[z][2] = M[z][1]*W[11] + M[z][2]*W[9]
                     + B[z][1]*W[3]  + B[z][2]*W[1]  + bb;
            o1[z][3] = M[z][2]*W[10] + M[z][3]*W[8]
                     + B[z][2]*W[2]  + B[z][3]*W[0]  + bb;
        }

        float* obase = out + ((size_t)(b * NS + s) * OHH + 2 * r) * OWW;
        #pragma unroll
        for (int z = 0; z < 2; ++z) {
            f32x4 v0 = { o0[z][0], o0[z][1], o0[z][2], o0[z][3] };
            f32x4 v1 = { o1[z][0], o1[z][1], o1[z][2], o1[z][3] };
            __builtin_nontemporal_store(v0, (f32x4*)(obase + z * 256 + 4 * t));
            __builtin_nontemporal_store(v1, (f32x4*)(obase + OWW + z * 256 + 4 * t));
        }
    }
}

extern "C" void kernel_launch(void* const* d_in, const int* in_sizes, int n_in,
                              void* d_out, int out_size, void* d_ws, size_t ws_size,
                              hipStream_t stream) {
    const float* x    = (const float*)d_in[0];
    const float* w    = (const float*)d_in[1];
    const float* bias = (const float*)d_in[2];
    float* out        = (float*)d_out;

    // per (b,s) image: 256 row-pairs / (4 waves x 4 pairs) = 16 blocks of 256
    dim3 grid(16, NS, 8);
    convt2x_roll_kernel<<<grid, 256, 0, stream>>>(x, w, bias, out);
}